// Round 5
// baseline (766.995 us; speedup 1.0000x reference)
//
#include <hip/hip_runtime.h>

typedef __bf16 bf16;
typedef __attribute__((ext_vector_type(8))) __bf16 bf16x8;
typedef __attribute__((ext_vector_type(4))) __bf16 bf16x4;
typedef __attribute__((ext_vector_type(2))) __bf16 bf16x2;
typedef __attribute__((ext_vector_type(4))) float floatx4;
typedef __attribute__((ext_vector_type(2))) float floatx2;

#define B_SZ 512
#define N_SZ 2048
#define DIN  784
#define DINP 800      // 784 padded to multiple of 32
#define ACT_LD 12288  // actsT row stride: 6 slices x 2048

// async global->LDS, 16B per lane (input-layer gemm only)
__device__ __forceinline__ void load_lds16(const bf16* g, bf16* l) {
    __builtin_amdgcn_global_load_lds(
        (const __attribute__((address_space(1))) void*)g,
        (__attribute__((address_space(3))) void*)l, 16, 0, 0);
}

// ---------------------------------------------------------------------------
// prep: x[512][784] -> xb[512][800] bf16 (zero pad), w_in[2048][784] -> w_inb
// ---------------------------------------------------------------------------
__global__ __launch_bounds__(256)
void prep_kernel(const float* __restrict__ x, const float* __restrict__ w_in,
                 bf16* __restrict__ xb, bf16* __restrict__ w_inb)
{
    int g = blockIdx.x * 256 + threadIdx.x;           // 512000 groups of 4
    const int GPR = DINP / 4;                         // 200 groups per row
    const float* src; bf16* dst; int row, c;
    if (g < B_SZ * GPR) {
        row = g / GPR; c = g - row * GPR;
        src = x + (size_t)row * DIN;  dst = xb + (size_t)row * DINP;
    } else {
        int h = g - B_SZ * GPR;
        row = h / GPR; c = h - row * GPR;
        src = w_in + (size_t)row * DIN;  dst = w_inb + (size_t)row * DINP;
    }
    int k = c * 4;
    floatx4 v = (floatx4){0.f, 0.f, 0.f, 0.f};
    if (k < DIN) v = *(const floatx4*)(src + k);      // 784 % 4 == 0
    bf16x4 o;
    o[0] = (bf16)v[0]; o[1] = (bf16)v[1]; o[2] = (bf16)v[2]; o[3] = (bf16)v[3];
    *(bf16x4*)(dst + k) = o;
}

// ---------------------------------------------------------------------------
// Input-layer GEMM (both operands bf16): 128x128 tile, BK=32, z K-chunks.
// ---------------------------------------------------------------------------
__global__ __launch_bounds__(256, 2)
void gemm_kernel(const bf16* __restrict__ A, int lda,
                 const bf16* __restrict__ Bm, int ldb,
                 float* __restrict__ partial,
                 int chunkK, int Ktot)
{
    __shared__ bf16 As[128 * 32];
    __shared__ bf16 Bs[128 * 32];

    const int t    = threadIdx.x;
    const int lane = t & 63, wave = t >> 6;
    const int wm   = (wave & 1) * 64, wn = (wave >> 1) * 64;
    const int l15  = lane & 15, quad = lane >> 4;
    const int n0   = blockIdx.x * 128, m0 = blockIdx.y * 128;
    const int s    = blockIdx.z;
    const int kb   = s * chunkK;
    const int ke   = (kb + chunkK < Ktot) ? (kb + chunkK) : Ktot;

    const int rA = wave * 16 + (lane >> 2);
    const int cA = (lane & 3) * 8;
    const bf16* pA0 = A  + (size_t)(m0 + rA) * lda + cA + kb;
    const bf16* pA1 = pA0 + (size_t)64 * lda;
    const bf16* pB0 = Bm + (size_t)(n0 + rA) * ldb + cA + kb;
    const bf16* pB1 = pB0 + (size_t)64 * ldb;
    bf16* dA0 = &As[wave * 512];  bf16* dA1 = &As[(wave + 4) * 512];
    bf16* dB0 = &Bs[wave * 512];  bf16* dB1 = &Bs[(wave + 4) * 512];

    floatx4 acc[4][4];
#pragma unroll
    for (int a = 0; a < 4; a++)
#pragma unroll
        for (int b = 0; b < 4; b++) acc[a][b] = (floatx4){0.f, 0.f, 0.f, 0.f};

    for (int k0 = kb; k0 < ke; k0 += 32) {
        __syncthreads();
        load_lds16(pA0, dA0);  load_lds16(pA1, dA1);
        load_lds16(pB0, dB0);  load_lds16(pB1, dB1);
        pA0 += 32; pA1 += 32; pB0 += 32; pB1 += 32;
        __syncthreads();

        bf16x8 af[4], bfr[4];
#pragma unroll
        for (int a = 0; a < 4; a++)
            af[a] = *(const bf16x8*)(&As[(wm + a * 16 + l15) * 32 + quad * 8]);
#pragma unroll
        for (int b = 0; b < 4; b++)
            bfr[b] = *(const bf16x8*)(&Bs[(wn + b * 16 + l15) * 32 + quad * 8]);
#pragma unroll
        for (int a = 0; a < 4; a++)
#pragma unroll
            for (int b = 0; b < 4; b++)
                acc[a][b] = __builtin_amdgcn_mfma_f32_16x16x32_bf16(af[a], bfr[b], acc[a][b], 0, 0, 0);
    }

    float* outp = partial + (size_t)s * (B_SZ * N_SZ);
#pragma unroll
    for (int a = 0; a < 4; a++)
#pragma unroll
        for (int b = 0; b < 4; b++)
#pragma unroll
            for (int r = 0; r < 4; r++) {
                int row = m0 + wm + a * 16 + quad * 4 + r;
                int col = n0 + wn + b * 16 + l15;
                outp[(size_t)row * N_SZ + col] = acc[a][b][r];
            }
}

// ---------------------------------------------------------------------------
// DAG GEMM v2: M-tile = 512 (FULL batch) x N-tile 32, BK=32, 512 threads.
// Each W/M element is fetched exactly once from HBM (no m-block redundancy).
// Register-staged, double-buffered LDS, 1 barrier/step, W/M/A prefetched one
// step ahead (plain VGPR loads survive __syncthreads; only lgkmcnt drains).
// Grid: (64 n-blocks) x (z=8 K-chunks) = 512 blocks, 2 blocks/CU (68 KB LDS).
// ---------------------------------------------------------------------------
__global__ __launch_bounds__(512, 4)
void dag_gemm_kernel(const bf16* __restrict__ A,
                     const float* __restrict__ Wl, const float* __restrict__ Ml,
                     float* __restrict__ partial,
                     int chunkK)
{
    __shared__ bf16 As[2][512 * 32];   // 32 KB x2
    __shared__ bf16 Bs[2][32 * 32];    //  2 KB x2

    const int t    = threadIdx.x;              // 0..511
    const int lane = t & 63, wave = t >> 6;    // 8 waves
    const int l15  = lane & 15, quad = lane >> 4;
    const int n0   = blockIdx.x * 32;
    const int kb   = blockIdx.z * chunkK;      // chunkK = 256*i, 8i steps (even)
    const int ke   = kb + chunkK;

    // A staging: 4 reps; rep r: row (t>>2)+r*128, k-seg (t&3)*8  (16 B)
    const int ar = t >> 2, ac = (t & 3) * 8;
    // B staging: n-row t>>4 (0..31), k-offset (t&15)*2 floats (8 B)
    const int brow = t >> 4, bk = (t & 15) * 2;
    const size_t wbase = (size_t)(n0 + brow) << 11;   // n*2048 within a pair

    floatx4 acc[4][2];
#pragma unroll
    for (int a = 0; a < 4; a++)
#pragma unroll
        for (int b = 0; b < 2; b++) acc[a][b] = (floatx4){0.f, 0.f, 0.f, 0.f};

    bf16x8 a0, a1, a2, a3;       // staged A
    floatx2 wv, mv;              // staged W/M

    auto load_regs = [&](int k) {
        const bf16* ap = A + (size_t)ar * ACT_LD + k + ac;
        a0 = *(const bf16x8*)(ap);
        a1 = *(const bf16x8*)(ap + (size_t)128 * ACT_LD);
        a2 = *(const bf16x8*)(ap + (size_t)256 * ACT_LD);
        a3 = *(const bf16x8*)(ap + (size_t)384 * ACT_LD);
        int jj = k >> 11, kk = k & 2047;       // BK tile never crosses a pair
        size_t o = ((size_t)jj << 22) + wbase + kk + bk;
        wv = *(const floatx2*)(Wl + o);
        mv = *(const floatx2*)(Ml + o);
    };

    auto do_step = [&](int buf, int knext, bool pref) {
        bf16x2 pp;
        pp[0] = (bf16)(wv[0] * mv[0]);
        pp[1] = (bf16)(wv[1] * mv[1]);
        *(bf16x2*)(&Bs[buf][brow * 32 + bk]) = pp;
        *(bf16x8*)(&As[buf][(ar +   0) * 32 + ac]) = a0;
        *(bf16x8*)(&As[buf][(ar + 128) * 32 + ac]) = a1;
        *(bf16x8*)(&As[buf][(ar + 256) * 32 + ac]) = a2;
        *(bf16x8*)(&As[buf][(ar + 384) * 32 + ac]) = a3;
        if (pref) load_regs(knext);            // stays in flight across barrier
        __syncthreads();
        bf16x8 af[4], bfr[2];
#pragma unroll
        for (int a = 0; a < 4; a++)
            af[a] = *(const bf16x8*)(&As[buf][(wave * 64 + a * 16 + l15) * 32 + quad * 8]);
#pragma unroll
        for (int b = 0; b < 2; b++)
            bfr[b] = *(const bf16x8*)(&Bs[buf][(b * 16 + l15) * 32 + quad * 8]);
#pragma unroll
        for (int a = 0; a < 4; a++)
#pragma unroll
            for (int b = 0; b < 2; b++)
                acc[a][b] = __builtin_amdgcn_mfma_f32_16x16x32_bf16(af[a], bfr[b], acc[a][b], 0, 0, 0);
    };

    load_regs(kb);
    for (int k0 = kb; k0 < ke; k0 += 64) {
        do_step(0, k0 + 32, true);
        do_step(1, k0 + 64, (k0 + 64) < ke);
    }

    // C/D layout: col = lane&15, row = quad*4 + reg
    float* outp = partial + (size_t)blockIdx.z * (B_SZ * N_SZ);
#pragma unroll
    for (int a = 0; a < 4; a++)
#pragma unroll
        for (int b = 0; b < 2; b++)
#pragma unroll
            for (int r = 0; r < 4; r++) {
                int row = wave * 64 + a * 16 + quad * 4 + r;
                int col = n0 + b * 16 + l15;
                outp[(size_t)row * N_SZ + col] = acc[a][b][r];
            }
}

// ---------------------------------------------------------------------------
// epilogue: actsT[b][slice*2048+n] = bf16(relu(sum_s partial[s][b][n] + bscale*bias[n]))
// ---------------------------------------------------------------------------
__global__ __launch_bounds__(256)
void epilogue_kernel(const float* __restrict__ partial, int S,
                     const float* __restrict__ bias, float bscale,
                     bf16* __restrict__ actdst)   // = actsT + slice*2048
{
    int g = blockIdx.x * 256 + threadIdx.x;       // 262144 groups of 4
    size_t off = (size_t)g * 4;
    int b = (int)(off >> 11);
    int n = (int)(off & (N_SZ - 1));
    floatx4 v = *(const floatx4*)(partial + off);
    for (int s2 = 1; s2 < S; s2++)
        v += *(const floatx4*)(partial + (size_t)s2 * (B_SZ * N_SZ) + off);
    floatx4 bv = *(const floatx4*)(bias + n);
    bf16x4 o;
#pragma unroll
    for (int j = 0; j < 4; j++) {
        float xv = v[j] + bscale * bv[j];
        xv = xv > 0.f ? xv : 0.f;
        o[j] = (bf16)xv;
    }
    *(bf16x4*)(actdst + (size_t)b * ACT_LD + n) = o;
}

// ---------------------------------------------------------------------------
// output: out[b,c] = act5[b]·w1[c] + b1[c] + act4[b]·w2[c] + b2[c]
// ---------------------------------------------------------------------------
__global__ __launch_bounds__(64)
void out_kernel(const bf16* __restrict__ act4, const bf16* __restrict__ act5,
                const float* __restrict__ w1, const float* __restrict__ b1,
                const float* __restrict__ w2, const float* __restrict__ b2,
                float* __restrict__ out)
{
    int b = blockIdx.x, lane = threadIdx.x;
    float a5[32], a4[32];
#pragma unroll
    for (int rep = 0; rep < 4; rep++) {
        bf16x8 v5 = *(const bf16x8*)(act5 + (size_t)b * ACT_LD + rep * 512 + lane * 8);
        bf16x8 v4 = *(const bf16x8*)(act4 + (size_t)b * ACT_LD + rep * 512 + lane * 8);
#pragma unroll
        for (int j = 0; j < 8; j++) {
            a5[rep * 8 + j] = (float)v5[j];
            a4[rep * 8 + j] = (float)v4[j];
        }
    }
    for (int c = 0; c < 10; c++) {
        float d = 0.f;
#pragma unroll
        for (int rep = 0; rep < 4; rep++) {
            floatx4 wa = *(const floatx4*)(w1 + (size_t)c * N_SZ + rep * 512 + lane * 8);
            floatx4 wb = *(const floatx4*)(w1 + (size_t)c * N_SZ + rep * 512 + lane * 8 + 4);
            floatx4 va = *(const floatx4*)(w2 + (size_t)c * N_SZ + rep * 512 + lane * 8);
            floatx4 vb = *(const floatx4*)(w2 + (size_t)c * N_SZ + rep * 512 + lane * 8 + 4);
#pragma unroll
            for (int j = 0; j < 4; j++) {
                d += a5[rep * 8 + j] * wa[j] + a4[rep * 8 + j] * va[j];
                d += a5[rep * 8 + 4 + j] * wb[j] + a4[rep * 8 + 4 + j] * vb[j];
            }
        }
        for (int off = 32; off > 0; off >>= 1) d += __shfl_down(d, off);
        if (lane == 0) out[b * 10 + c] = d + b1[c] + b2[c];
    }
}

// ---------------------------------------------------------------------------
extern "C" void kernel_launch(void* const* d_in, const int* in_sizes, int n_in,
                              void* d_out, int out_size, void* d_ws, size_t ws_size,
                              hipStream_t stream)
{
    const float* x    = (const float*)d_in[0];
    const float* w_in = (const float*)d_in[1];
    const float* b_in = (const float*)d_in[2];
    const float* W    = (const float*)d_in[3];
    const float* M    = (const float*)d_in[4];
    const float* bL   = (const float*)d_in[5];
    const float* w1   = (const float*)d_in[6];
    const float* b1   = (const float*)d_in[7];
    const float* w2   = (const float*)d_in[8];
    const float* b2   = (const float*)d_in[9];
    float* out = (float*)d_out;

    // workspace layout (all 16B-aligned):
    //   xb     @ 0        : 512*800*2    =    819200
    //   w_inb  @ 819200   : 2048*800*2   =   3276800
    //   actsT  @ 4096000  : 512*12288*2  =  12582912
    //   partial@ 16678912 : 8*512*2048*4 =  33554432   (end ~50 MB)
    char* ws = (char*)d_ws;
    bf16*  xb      = (bf16*)ws;
    bf16*  w_inb   = (bf16*)(ws + 819200);
    bf16*  actsT   = (bf16*)(ws + 4096000);
    float* partial = (float*)(ws + 16678912);

    prep_kernel<<<2000, 256, 0, stream>>>(x, w_in, xb, w_inb);

    // input layer: A=xb [512x800], B=w_inb [2048x800], z=4 chunks of 224
    gemm_kernel<<<dim3(16, 4, 4), 256, 0, stream>>>(
        xb, DINP, w_inb, DINP, partial, 224, DINP);
    epilogue_kernel<<<1024, 256, 0, stream>>>(partial, 4, b_in, 1.0f, actsT);

    // DAG layers: fused W*M, full-batch M-tile; grid (64 n, 1, 8 z) = 512 blocks
    for (int i = 1; i < 6; i++) {
        int idx = i * (i - 1) / 2;
        const float* Wl = W + ((size_t)idx << 22);
        const float* Ml = M + ((size_t)idx << 22);
        dag_gemm_kernel<<<dim3(64, 1, 8), 512, 0, stream>>>(
            actsT, Wl, Ml, partial, 256 * i);
        epilogue_kernel<<<1024, 256, 0, stream>>>(
            partial, 8, bL + (size_t)(i - 1) * N_SZ, (float)i,
            actsT + (size_t)i * N_SZ);
    }

    out_kernel<<<512, 64, 0, stream>>>(
        actsT + (size_t)4 * N_SZ, actsT + (size_t)5 * N_SZ,
        w1, b1, w2, b2, out);
}